// Round 2
// baseline (231.214 us; speedup 1.0000x reference)
//
#include <hip/hip_runtime.h>

// RandomShifts: out[n,c,i,j] = x[n,c, clamp(i+dy,0,83), clamp(j+dx,0,83)],
// dx = sx-4, dy = sy-4.  x: (512,9,84,84) fp32, shift: (512,2) int32.
// Memory-bound: 130 MB read (L3-warm) + 130 MB write.

#define PADN 4
#define NB   512
#define CB   9
#define HB   84
#define WB   84
#define W4   21            // float4s per row
#define IMG_F4 (HB * W4)   // 1764 float4s per (n,c) image

// 4-byte-aligned 16-byte access (dwordx4 needs only dword alignment on CDNA)
struct __attribute__((packed, aligned(4))) f4u { float a, b, c, d; };

__device__ __forceinline__ float4 load_shifted(const float* __restrict__ srow, int cs) {
    if (cs >= 0 && cs <= WB - 4) {
        const f4u u = *reinterpret_cast<const f4u*>(srow + cs);
        return make_float4(u.a, u.b, u.c, u.d);
    }
    // row edge (only j4==0 with dx<0, or j4==20 with dx>0): replicate clamp
    const int c0 = min(max(cs,     0), WB - 1);
    const int c1 = min(max(cs + 1, 0), WB - 1);
    const int c2 = min(max(cs + 2, 0), WB - 1);
    const int c3 = min(max(cs + 3, 0), WB - 1);
    return make_float4(srow[c0], srow[c1], srow[c2], srow[c3]);
}

__global__ __launch_bounds__(256) void random_shifts_kernel(
    const float* __restrict__ x,
    const int*   __restrict__ shift,
    float*       __restrict__ out)
{
    const int nc = blockIdx.x;            // one block per (n,c) image: 4608 blocks
    const int n  = nc / CB;               // wave-uniform -> scalar loads for shift
    const int dx = shift[2 * n]     - PADN;   // [-4, 4]
    const int dy = shift[2 * n + 1] - PADN;   // [-4, 4]

    const float* __restrict__ img = x   + (size_t)nc * (HB * WB);
    float*       __restrict__ dst = out + (size_t)nc * (HB * WB);
    const int tid = threadIdx.x;

#pragma unroll
    for (int k = 0; k < 6; ++k) {         // 6*256 = 1536 full iterations
        const int fid = tid + (k << 8);
        const int i   = fid / W4;
        const int j4  = fid - i * W4;
        int si = i + dy;
        si = min(max(si, 0), HB - 1);
        const float* srow = img + si * WB;
        const float4 v = load_shifted(srow, (j4 << 2) + dx);
        *reinterpret_cast<float4*>(dst + ((size_t)fid << 2)) = v;
    }
    // tail: fids 1536..1763
    {
        const int fid = tid + (6 << 8);
        if (fid < IMG_F4) {
            const int i  = fid / W4;
            const int j4 = fid - i * W4;
            int si = i + dy;
            si = min(max(si, 0), HB - 1);
            const float* srow = img + si * WB;
            const float4 v = load_shifted(srow, (j4 << 2) + dx);
            *reinterpret_cast<float4*>(dst + ((size_t)fid << 2)) = v;
        }
    }
}

extern "C" void kernel_launch(void* const* d_in, const int* in_sizes, int n_in,
                              void* d_out, int out_size, void* d_ws, size_t ws_size,
                              hipStream_t stream) {
    const float* x     = (const float*)d_in[0];
    const int*   shift = (const int*)d_in[1];
    float*       out   = (float*)d_out;

    random_shifts_kernel<<<NB * CB, 256, 0, stream>>>(x, shift, out);
}